// Round 5
// baseline (301.221 us; speedup 1.0000x reference)
//
#include <hip/hip_runtime.h>
#include <hip/hip_bf16.h>

typedef __bf16 bf16;
typedef __bf16 bf16x8 __attribute__((ext_vector_type(8)));
typedef float f32x4 __attribute__((ext_vector_type(4)));
typedef unsigned short u16;
typedef u16 u16x4 __attribute__((ext_vector_type(4)));

#define MFMA16(a, b, c) __builtin_amdgcn_mfma_f32_16x16x32_bf16(a, b, c, 0, 0, 0)

// ---- problem constants ----
// B=8, T_NEW=128, E=1024, H=16, HD=64, NB=10, TPREV=4096, T=4224
// chunking: SPLIT=6 chunks of 704 keys = 11 tiles of 64
static __device__ __forceinline__ bf16x8 cvt8(float4 a, float4 b) {
  union { bf16 h[8]; bf16x8 v; } u;
  u.h[0] = (bf16)a.x; u.h[1] = (bf16)a.y; u.h[2] = (bf16)a.z; u.h[3] = (bf16)a.w;
  u.h[4] = (bf16)b.x; u.h[5] = (bf16)b.y; u.h[6] = (bf16)b.z; u.h[7] = (bf16)b.w;
  return u.v;
}

// ============ LayerNorm: X (1024 rows x 1024) f32 -> Xn bf16 ============
__global__ __launch_bounds__(256) void k_ln(const float* __restrict__ X,
                                            const float* __restrict__ g,
                                            const float* __restrict__ bb,
                                            bf16* __restrict__ Xn) {
  int m = blockIdx.x, t = threadIdx.x;
  const float* row = X + (size_t)m * 1024;
  float4 x = ((const float4*)row)[t];
  float s1 = x.x + x.y + x.z + x.w;
  float s2 = x.x * x.x + x.y * x.y + x.z * x.z + x.w * x.w;
#pragma unroll
  for (int off = 1; off < 64; off <<= 1) {
    s1 += __shfl_xor(s1, off);
    s2 += __shfl_xor(s2, off);
  }
  __shared__ float ws1[4], ws2[4];
  int w = t >> 6;
  if ((t & 63) == 0) { ws1[w] = s1; ws2[w] = s2; }
  __syncthreads();
  s1 = ws1[0] + ws1[1] + ws1[2] + ws1[3];
  s2 = ws2[0] + ws2[1] + ws2[2] + ws2[3];
  float mu = s1 * (1.f / 1024.f);
  float var = s2 * (1.f / 1024.f) - mu * mu;
  float rstd = rsqrtf(var + 1e-5f);
  float4 gg = ((const float4*)g)[t];
  float4 bv = ((const float4*)bb)[t];
  union { bf16 h[4]; u16x4 v; } u;
  u.h[0] = (bf16)((x.x - mu) * rstd * gg.x + bv.x);
  u.h[1] = (bf16)((x.y - mu) * rstd * gg.y + bv.y);
  u.h[2] = (bf16)((x.z - mu) * rstd * gg.z + bv.z);
  u.h[3] = (bf16)((x.w - mu) * rstd * gg.w + bv.w);
  ((u16x4*)(Xn + (size_t)m * 1024))[t] = u.v;
}

// ============ weight convert+transpose ============
__global__ __launch_bounds__(256) void k_convert(const float* __restrict__ Wq,
                                                 const float* __restrict__ Wk,
                                                 const float* __restrict__ Wv,
                                                 const float* __restrict__ Wr,
                                                 const float* __restrict__ Wp,
                                                 bf16* __restrict__ Wt_all,
                                                 bf16* __restrict__ Wpt) {
  __shared__ float tile[64][65];
  int t = threadIdx.x;
  int bn = blockIdx.x / 16, bk = blockIdx.x % 16;
  int n0 = bn * 64, k0 = bk * 64;
#pragma unroll
  for (int it = 0; it < 16; ++it) {
    int idx = t + 256 * it;
    int kl = idx >> 6, nl = idx & 63;
    int n = n0 + nl, k = k0 + kl;
    float v;
    if (n < 1024)       v = Wq[(size_t)k * 1024 + n];
    else if (n < 2048)  v = Wk[(size_t)k * 1024 + (n - 1024)];
    else if (n < 3072)  v = Wv[(size_t)k * 1024 + (n - 2048)];
    else if (n < 3232)  v = Wr[(size_t)k * 160 + (n - 3072)];
    else if (n < 3328)  v = 0.f;
    else                v = Wp[(size_t)k * 1024 + (n - 3328)];
    tile[kl][nl] = v;
  }
  __syncthreads();
#pragma unroll
  for (int it = 0; it < 16; ++it) {
    int idx = t + 256 * it;
    int nl = idx >> 6, kl = idx & 63;
    int n = n0 + nl, k = k0 + kl;
    bf16 v = (bf16)tile[kl][nl];
    if (n < 3328) Wt_all[(size_t)n * 1024 + k] = v;
    else          Wpt[(size_t)(n - 3328) * 1024 + k] = v;
  }
}

// ============ GEMM: C[m][n] = sum_k A[m][k]*Wt[n][k], K=1024, M=1024 ============
template <int MODE>
__global__ __launch_bounds__(256) void k_gemm(const bf16* __restrict__ A,
                                              const bf16* __restrict__ Bw,
                                              bf16* __restrict__ Qb, bf16* __restrict__ Kn,
                                              bf16* __restrict__ Vn, float* __restrict__ Rws,
                                              const float* __restrict__ bq,
                                              const float* __restrict__ br,
                                              float* __restrict__ Out,
                                              const float* __restrict__ bproj,
                                              const float* __restrict__ Xres) {
  __shared__ __align__(16) bf16 As[128][72];
  __shared__ __align__(16) bf16 Bs[128][72];
  int t = threadIdx.x, l = t & 63, wid = t >> 6;
  int ln = l & 15, grp = l >> 4;
  int m0 = blockIdx.y * 128, n0 = blockIdx.x * 128;
  int wr = wid >> 1, wc = wid & 1;
  f32x4 acc[4][4] = {};
  int srow = t >> 1, shalf = (t & 1) * 32;

  for (int kt = 0; kt < 16; ++kt) {
    int k0 = kt * 64;
    const bf16* asrc = A + (size_t)(m0 + srow) * 1024 + k0 + shalf;
    const bf16* bsrc = Bw + (size_t)(n0 + srow) * 1024 + k0 + shalf;
    bf16x8 a0 = ((const bf16x8*)asrc)[0], a1 = ((const bf16x8*)asrc)[1];
    bf16x8 a2 = ((const bf16x8*)asrc)[2], a3 = ((const bf16x8*)asrc)[3];
    bf16x8 b0 = ((const bf16x8*)bsrc)[0], b1 = ((const bf16x8*)bsrc)[1];
    bf16x8 b2 = ((const bf16x8*)bsrc)[2], b3 = ((const bf16x8*)bsrc)[3];
    __syncthreads();
    *(bf16x8*)&As[srow][shalf + 0] = a0;  *(bf16x8*)&As[srow][shalf + 8] = a1;
    *(bf16x8*)&As[srow][shalf + 16] = a2; *(bf16x8*)&As[srow][shalf + 24] = a3;
    *(bf16x8*)&Bs[srow][shalf + 0] = b0;  *(bf16x8*)&Bs[srow][shalf + 8] = b1;
    *(bf16x8*)&Bs[srow][shalf + 16] = b2; *(bf16x8*)&Bs[srow][shalf + 24] = b3;
    __syncthreads();
#pragma unroll
    for (int ks = 0; ks < 2; ++ks) {
      int kk = ks * 32 + grp * 8;
      bf16x8 af[4], bf[4];
#pragma unroll
      for (int is = 0; is < 4; ++is) af[is] = *(const bf16x8*)&As[wr * 64 + is * 16 + ln][kk];
#pragma unroll
      for (int js = 0; js < 4; ++js) bf[js] = *(const bf16x8*)&Bs[wc * 64 + js * 16 + ln][kk];
#pragma unroll
      for (int is = 0; is < 4; ++is)
#pragma unroll
        for (int js = 0; js < 4; ++js) acc[is][js] = MFMA16(af[is], bf[js], acc[is][js]);
    }
  }

#pragma unroll
  for (int is = 0; is < 4; ++is)
#pragma unroll
    for (int js = 0; js < 4; ++js)
#pragma unroll
      for (int r = 0; r < 4; ++r) {
        int m = m0 + wr * 64 + is * 16 + grp * 4 + r;
        int n = n0 + wc * 64 + js * 16 + ln;
        float v = acc[is][js][r];
        if (MODE == 0) {
          int b = m >> 7, il = m & 127;
          if (n < 1024) {
            int h = n >> 6, dm = n & 63;
            Qb[((size_t)(b * 16 + h) * 128 + il) * 64 + dm] = (bf16)((v + bq[n]) * 0.125f);
          } else if (n < 2048) {
            Kn[(size_t)m * 1024 + (n - 1024)] = (bf16)v;
          } else if (n < 3072) {
            Vn[(size_t)m * 1024 + (n - 2048)] = (bf16)v;
          } else if (n < 3232) {
            int e = n - 3072, hh = e / 10, nb = e - hh * 10;
            Rws[((size_t)(b * 16 + hh) * 128 + il) * 10 + nb] = v + br[e];
          }
        } else {
          Out[(size_t)m * 1024 + n] = v + bproj[n] + Xres[(size_t)m * 1024 + n];
        }
      }
}

// ============ attention: grid = 128 bh * 6 chunks, 512 threads ============
// 2 barriers/tile; per-wave G window folded IN PLACE into Sacc (no vals[] array);
// P aliased into Gw (LDS ~49KB -> 3 blocks/CU at <=85 VGPR).
__global__ __launch_bounds__(512, 6) void k_attn(const float* __restrict__ cacheK,
                                                 const float* __restrict__ cacheV,
                                                 const bf16* __restrict__ Kn,
                                                 const bf16* __restrict__ Vn,
                                                 const bf16* __restrict__ Qb,
                                                 const float* __restrict__ Rws,
                                                 const float* __restrict__ bnd,
                                                 float* __restrict__ Opart,
                                                 float* __restrict__ mws,
                                                 float* __restrict__ lws) {
  __shared__ __align__(16) bf16 Ks[64][72];
  __shared__ __align__(16) bf16 Vt[64][72];       // Vt[d][j]
  __shared__ __align__(16) bf16 Gw[8][80][20];    // per-wave: [c_local][i_local]; P reuses this
  __shared__ __align__(16) bf16 bT[192][16];      // bT[c][n] = bnd[n][dlo+c]

  int t = threadIdx.x, l = t & 63, w = t >> 6;
  int grp = l >> 4, ln = l & 15;
  int s = blockIdx.x % 6, bh = blockIdx.x / 6;
  int b = bh >> 4, h = bh & 15;

  if (t < 192) {
#pragma unroll
    for (int e = 10; e < 16; ++e) bT[t][e] = (bf16)0.f;
  }

  int iq = w * 16 + ln;
  bf16x8 qf[2];
  qf[0] = *(const bf16x8*)(Qb + ((size_t)bh * 128 + iq) * 64 + grp * 8);
  qf[1] = *(const bf16x8*)(Qb + ((size_t)bh * 128 + iq) * 64 + 32 + grp * 8);
  bf16x8 rf;
  {
    union { bf16 hh[8]; bf16x8 v; } u;
    const float* rrow = Rws + ((size_t)bh * 128 + iq) * 10;
#pragma unroll
    for (int e = 0; e < 8; ++e) {
      int k = grp * 8 + e;
      u.hh[e] = (bf16)(k < 10 ? rrow[k] : 0.f);
    }
    rf = u.v;
  }

  // staging thread roles
  int krow = t >> 3, kcb = (t & 7) * 8;   // K: 64 rows x 8 col-blocks
  int vjl = t & 63, vd0 = (t >> 6) * 8;   // V: 64 j x 8 d-blocks
  int bc = t >> 1, bnh = (t & 1) * 5;     // bnd: threads<384, 5 basis each

  // uniform fp32 double-buffer staging regs
  float4 kA, kB, vA, vB;
  float bnv[5];

  auto issue = [&](int jt0) {
    if (jt0 < 4096) {
      const float* src = cacheK + ((size_t)(b * 4096 + jt0 + krow)) * 1024 + h * 64 + kcb;
      kA = *(const float4*)src;
      kB = *(const float4*)(src + 4);
      const float* sv = cacheV + ((size_t)(b * 4096 + jt0 + vjl)) * 1024 + h * 64 + vd0;
      vA = *(const float4*)sv;
      vB = *(const float4*)(sv + 4);
    } else {
      // new-token tiles (L2-hot, minority path): convert bf16 -> fp32 staging regs
      bf16x8 kN = *(const bf16x8*)(Kn + ((size_t)(b * 128 + (jt0 + krow - 4096))) * 1024 + h * 64 + kcb);
      bf16x8 vN = *(const bf16x8*)(Vn + ((size_t)(b * 128 + (jt0 + vjl - 4096))) * 1024 + h * 64 + vd0);
      kA = make_float4((float)kN[0], (float)kN[1], (float)kN[2], (float)kN[3]);
      kB = make_float4((float)kN[4], (float)kN[5], (float)kN[6], (float)kN[7]);
      vA = make_float4((float)vN[0], (float)vN[1], (float)vN[2], (float)vN[3]);
      vB = make_float4((float)vN[4], (float)vN[5], (float)vN[6], (float)vN[7]);
    }
    if (t < 384) {
      int d = (4033 - jt0) + bc;
      d = d < 0 ? 0 : (d > 4095 ? 4095 : d);
#pragma unroll
      for (int k = 0; k < 5; ++k) bnv[k] = bnd[(size_t)(bnh + k) * 4096 + d];
    }
  };

  issue(s * 704);

  f32x4 Oacc[4] = {};
  float m_r[4], l_r[4];
#pragma unroll
  for (int r = 0; r < 4; ++r) { m_r[r] = -1e30f; l_r[r] = 0.f; }

  for (int tt = 0; tt < 11; ++tt) {
    int jt0 = s * 704 + tt * 64;
    __syncthreads();                 // all waves done reading previous tile's LDS
    // ---- write staged regs -> LDS (uniform path) ----
    *(bf16x8*)&Ks[krow][kcb] = cvt8(kA, kB);
    Vt[vd0 + 0][vjl] = (bf16)vA.x; Vt[vd0 + 1][vjl] = (bf16)vA.y;
    Vt[vd0 + 2][vjl] = (bf16)vA.z; Vt[vd0 + 3][vjl] = (bf16)vA.w;
    Vt[vd0 + 4][vjl] = (bf16)vB.x; Vt[vd0 + 5][vjl] = (bf16)vB.y;
    Vt[vd0 + 6][vjl] = (bf16)vB.z; Vt[vd0 + 7][vjl] = (bf16)vB.w;
    if (t < 384) {
#pragma unroll
      for (int k = 0; k < 5; ++k) bT[bc][bnh + k] = (bf16)bnv[k];
    }
    __syncthreads();                 // staging visible to all
    if (tt + 1 < 11) issue(jt0 + 64);  // prefetch next tile

    // ---- S = Q @ K^T ----
    __builtin_amdgcn_s_setprio(1);
    f32x4 Sacc[4] = {};
#pragma unroll
    for (int ks = 0; ks < 2; ++ks) {
      int kk = ks * 32 + grp * 8;
#pragma unroll
      for (int js = 0; js < 4; ++js) {
        bf16x8 bfr = *(const bf16x8*)&Ks[js * 16 + ln][kk];
        Sacc[js] = MFMA16(qf[ks], bfr, Sacc[js]);
      }
    }
    // ---- per-wave G window: c in [w*16, w*16+80) ----
#pragma unroll
    for (int u = 0; u < 5; ++u) {
      bf16x8 bfr = *(const bf16x8*)&bT[(w + u) * 16 + ln][grp * 8];
      f32x4 z = {};
      f32x4 g = MFMA16(rf, bfr, z);
      union { bf16 hh[4]; u16x4 v; } uu;
      uu.hh[0] = (bf16)g[0]; uu.hh[1] = (bf16)g[1];
      uu.hh[2] = (bf16)g[2]; uu.hh[3] = (bf16)g[3];
      *(u16x4*)&Gw[w][u * 16 + ln][grp * 4] = uu.v;
    }
    __builtin_amdgcn_s_setprio(0);

    // ---- fold G + mask into Sacc IN PLACE (all Gw reads before any P write) ----
#pragma unroll
    for (int r = 0; r < 4; ++r) {
      int irow = grp * 4 + r;
      int il = w * 16 + irow;
#pragma unroll
      for (int js = 0; js < 4; ++js) {
        int jj = js * 16 + ln;
        int d = 4096 + il - (jt0 + jj);
        bool valid = ((unsigned)d) < 4096u;
        int cl = 63 + irow - jj;          // in [0,79) always
        float g = (float)Gw[w][cl][irow];
        Sacc[js][r] = valid ? (Sacc[js][r] + g) : -1e9f;
      }
    }
    // ---- online softmax; write P into Gw[w] region (wave-private) ----
    bf16* Pw = (bf16*)&Gw[w][0][0];    // P[i_local][j], pitch 72
#pragma unroll
    for (int r = 0; r < 4; ++r) {
      int irow = grp * 4 + r;
      float mx = fmaxf(fmaxf(Sacc[0][r], Sacc[1][r]), fmaxf(Sacc[2][r], Sacc[3][r]));
#pragma unroll
      for (int off = 1; off < 16; off <<= 1) mx = fmaxf(mx, __shfl_xor(mx, off));
      float mnew = fmaxf(m_r[r], mx);
      float sc = __expf(m_r[r] - mnew);
      m_r[r] = mnew;
      float rs = 0.f;
#pragma unroll
      for (int js = 0; js < 4; ++js) {
        float p = __expf(Sacc[js][r] - mnew);
        rs += p;
        Pw[irow * 72 + js * 16 + ln] = (bf16)p;
      }
#pragma unroll
      for (int off = 1; off < 16; off <<= 1) rs += __shfl_xor(rs, off);
      l_r[r] = l_r[r] * sc + rs;
#pragma unroll
      for (int ds = 0; ds < 4; ++ds) Oacc[ds][r] *= sc;
    }

    // ---- O += P @ V (reads own wave's P; same-wave DS ordering) ----
    __builtin_amdgcn_s_setprio(1);
    {
      bf16x8 pa0 = *(const bf16x8*)&Pw[ln * 72 + grp * 8];
      bf16x8 pa1 = *(const bf16x8*)&Pw[ln * 72 + 32 + grp * 8];
#pragma unroll
      for (int ds = 0; ds < 4; ++ds) {
        bf16x8 v0 = *(const bf16x8*)&Vt[ds * 16 + ln][grp * 8];
        bf16x8 v1 = *(const bf16x8*)&Vt[ds * 16 + ln][32 + grp * 8];
        Oacc[ds] = MFMA16(pa0, v0, Oacc[ds]);
        Oacc[ds] = MFMA16(pa1, v1, Oacc[ds]);
      }
    }
    __builtin_amdgcn_s_setprio(0);
  }

  int part = s * 128 + bh;
#pragma unroll
  for (int ds = 0; ds < 4; ++ds)
#pragma unroll
    for (int r = 0; r < 4; ++r) {
      int il = w * 16 + grp * 4 + r;
      Opart[((size_t)part * 128 + il) * 64 + ds * 16 + ln] = Oacc[ds][r];
    }
  if (ln == 0) {
#pragma unroll
    for (int r = 0; r < 4; ++r) {
      int il = w * 16 + grp * 4 + r;
      mws[(size_t)part * 128 + il] = m_r[r];
      lws[(size_t)part * 128 + il] = l_r[r];
    }
  }
}

// ============ split-K combine -> A (merged heads, bf16) ============
__global__ __launch_bounds__(256) void k_combine(const float* __restrict__ Opart,
                                                 const float* __restrict__ mws,
                                                 const float* __restrict__ lws,
                                                 bf16* __restrict__ Aout) {
  int bh = blockIdx.x, q = blockIdx.y, t = threadIdx.x;
  int dm = t & 63, iq = t >> 6;
  int b = bh >> 4, h = bh & 15;
  for (int ii = 0; ii < 8; ++ii) {
    int i = q * 32 + iq * 8 + ii;
    float ms[6], M = -1e30f;
#pragma unroll
    for (int s = 0; s < 6; ++s) {
      ms[s] = mws[(size_t)(s * 128 + bh) * 128 + i];
      M = fmaxf(M, ms[s]);
    }
    float L = 0.f, acc = 0.f;
#pragma unroll
    for (int s = 0; s < 6; ++s) {
      float wgt = __expf(ms[s] - M);
      L += wgt * lws[(size_t)(s * 128 + bh) * 128 + i];
      acc += wgt * Opart[((size_t)(s * 128 + bh) * 128 + i) * 64 + dm];
    }
    Aout[((size_t)(b * 128 + i)) * 1024 + h * 64 + dm] = (bf16)(acc / L);
  }
}

extern "C" void kernel_launch(void* const* d_in, const int* in_sizes, int n_in,
                              void* d_out, int out_size, void* d_ws, size_t ws_size,
                              hipStream_t stream) {
  (void)in_sizes; (void)n_in; (void)out_size; (void)ws_size;
  const float* X      = (const float*)d_in[0];
  const float* cacheK = (const float*)d_in[1];
  const float* cacheV = (const float*)d_in[2];
  const float* Wq     = (const float*)d_in[3];
  const float* bq     = (const float*)d_in[4];
  const float* Wk     = (const float*)d_in[5];
  const float* Wv     = (const float*)d_in[6];
  const float* Wproj  = (const float*)d_in[7];
  const float* bproj  = (const float*)d_in[8];
  const float* Wr     = (const float*)d_in[9];
  const float* br     = (const float*)d_in[10];
  const float* bnd    = (const float*)d_in[11];
  const float* lng    = (const float*)d_in[12];
  const float* lnb    = (const float*)d_in[13];
  float* out = (float*)d_out;

  char* ws = (char*)d_ws;
  bf16* Wt_all = (bf16*)ws;  ws += (size_t)3328 * 1024 * 2;
  bf16* Wpt    = (bf16*)ws;  ws += (size_t)1024 * 1024 * 2;
  bf16* Xn     = (bf16*)ws;  ws += (size_t)1024 * 1024 * 2;
  bf16* Qb     = (bf16*)ws;  ws += (size_t)1024 * 1024 * 2;
  bf16* Kn     = (bf16*)ws;  ws += (size_t)1024 * 1024 * 2;
  bf16* Vn     = (bf16*)ws;  ws += (size_t)1024 * 1024 * 2;
  bf16* Aattn  = (bf16*)ws;  ws += (size_t)1024 * 1024 * 2;
  float* Rws   = (float*)ws; ws += (size_t)128 * 128 * 10 * 4;
  float* mws   = (float*)ws; ws += (size_t)6 * 128 * 128 * 4;
  float* lws   = (float*)ws; ws += (size_t)6 * 128 * 128 * 4;
  float* Opart = (float*)ws; ws += (size_t)6 * 128 * 128 * 64 * 4;

  k_convert<<<dim3(68 * 16), 256, 0, stream>>>(Wq, Wk, Wv, Wr, Wproj, Wt_all, Wpt);
  k_ln<<<dim3(1024), 256, 0, stream>>>(X, lng, lnb, Xn);
  k_gemm<0><<<dim3(26, 8), 256, 0, stream>>>(Xn, Wt_all, Qb, Kn, Vn, Rws, bq, br,
                                             nullptr, nullptr, nullptr);
  k_attn<<<dim3(768), 512, 0, stream>>>(cacheK, cacheV, Kn, Vn, Qb, Rws, bnd,
                                        Opart, mws, lws);
  k_combine<<<dim3(128, 4), 256, 0, stream>>>(Opart, mws, lws, Aattn);
  k_gemm<1><<<dim3(8, 8), 256, 0, stream>>>(Aattn, Wpt, nullptr, nullptr, nullptr,
                                            nullptr, nullptr, nullptr, out, bproj, X);
}

// Round 6
// 190.096 us; speedup vs baseline: 1.5846x; 1.5846x over previous
//
#include <hip/hip_runtime.h>
#include <hip/hip_bf16.h>

typedef __bf16 bf16;
typedef __bf16 bf16x8 __attribute__((ext_vector_type(8)));
typedef float f32x4 __attribute__((ext_vector_type(4)));
typedef unsigned short u16;
typedef u16 u16x4 __attribute__((ext_vector_type(4)));

#define MFMA16(a, b, c) __builtin_amdgcn_mfma_f32_16x16x32_bf16(a, b, c, 0, 0, 0)

// ---- problem constants ----
// B=8, T_NEW=128, E=1024, H=16, HD=64, NB=10, TPREV=4096, T=4224
// chunking: SPLIT=6 chunks of 704 keys = 11 tiles of 64
static __device__ __forceinline__ bf16x8 cvt8(float4 a, float4 b) {
  union { bf16 h[8]; bf16x8 v; } u;
  u.h[0] = (bf16)a.x; u.h[1] = (bf16)a.y; u.h[2] = (bf16)a.z; u.h[3] = (bf16)a.w;
  u.h[4] = (bf16)b.x; u.h[5] = (bf16)b.y; u.h[6] = (bf16)b.z; u.h[7] = (bf16)b.w;
  return u.v;
}

// ============ LayerNorm: X (1024 rows x 1024) f32 -> Xn bf16 ============
__global__ __launch_bounds__(256) void k_ln(const float* __restrict__ X,
                                            const float* __restrict__ g,
                                            const float* __restrict__ bb,
                                            bf16* __restrict__ Xn) {
  int m = blockIdx.x, t = threadIdx.x;
  const float* row = X + (size_t)m * 1024;
  float4 x = ((const float4*)row)[t];
  float s1 = x.x + x.y + x.z + x.w;
  float s2 = x.x * x.x + x.y * x.y + x.z * x.z + x.w * x.w;
#pragma unroll
  for (int off = 1; off < 64; off <<= 1) {
    s1 += __shfl_xor(s1, off);
    s2 += __shfl_xor(s2, off);
  }
  __shared__ float ws1[4], ws2[4];
  int w = t >> 6;
  if ((t & 63) == 0) { ws1[w] = s1; ws2[w] = s2; }
  __syncthreads();
  s1 = ws1[0] + ws1[1] + ws1[2] + ws1[3];
  s2 = ws2[0] + ws2[1] + ws2[2] + ws2[3];
  float mu = s1 * (1.f / 1024.f);
  float var = s2 * (1.f / 1024.f) - mu * mu;
  float rstd = rsqrtf(var + 1e-5f);
  float4 gg = ((const float4*)g)[t];
  float4 bv = ((const float4*)bb)[t];
  union { bf16 h[4]; u16x4 v; } u;
  u.h[0] = (bf16)((x.x - mu) * rstd * gg.x + bv.x);
  u.h[1] = (bf16)((x.y - mu) * rstd * gg.y + bv.y);
  u.h[2] = (bf16)((x.z - mu) * rstd * gg.z + bv.z);
  u.h[3] = (bf16)((x.w - mu) * rstd * gg.w + bv.w);
  ((u16x4*)(Xn + (size_t)m * 1024))[t] = u.v;
}

// ============ weight convert+transpose ============
__global__ __launch_bounds__(256) void k_convert(const float* __restrict__ Wq,
                                                 const float* __restrict__ Wk,
                                                 const float* __restrict__ Wv,
                                                 const float* __restrict__ Wr,
                                                 const float* __restrict__ Wp,
                                                 bf16* __restrict__ Wt_all,
                                                 bf16* __restrict__ Wpt) {
  __shared__ float tile[64][65];
  int t = threadIdx.x;
  int bn = blockIdx.x / 16, bk = blockIdx.x % 16;
  int n0 = bn * 64, k0 = bk * 64;
#pragma unroll
  for (int it = 0; it < 16; ++it) {
    int idx = t + 256 * it;
    int kl = idx >> 6, nl = idx & 63;
    int n = n0 + nl, k = k0 + kl;
    float v;
    if (n < 1024)       v = Wq[(size_t)k * 1024 + n];
    else if (n < 2048)  v = Wk[(size_t)k * 1024 + (n - 1024)];
    else if (n < 3072)  v = Wv[(size_t)k * 1024 + (n - 2048)];
    else if (n < 3232)  v = Wr[(size_t)k * 160 + (n - 3072)];
    else if (n < 3328)  v = 0.f;
    else                v = Wp[(size_t)k * 1024 + (n - 3328)];
    tile[kl][nl] = v;
  }
  __syncthreads();
#pragma unroll
  for (int it = 0; it < 16; ++it) {
    int idx = t + 256 * it;
    int nl = idx >> 6, kl = idx & 63;
    int n = n0 + nl, k = k0 + kl;
    bf16 v = (bf16)tile[kl][nl];
    if (n < 3328) Wt_all[(size_t)n * 1024 + k] = v;
    else          Wpt[(size_t)(n - 3328) * 1024 + k] = v;
  }
}

// ============ GEMM: C[m][n] = sum_k A[m][k]*Wt[n][k], K=1024, M=1024 ============
template <int MODE>
__global__ __launch_bounds__(256) void k_gemm(const bf16* __restrict__ A,
                                              const bf16* __restrict__ Bw,
                                              bf16* __restrict__ Qb, bf16* __restrict__ Kn,
                                              bf16* __restrict__ Vn, float* __restrict__ Rws,
                                              const float* __restrict__ bq,
                                              const float* __restrict__ br,
                                              float* __restrict__ Out,
                                              const float* __restrict__ bproj,
                                              const float* __restrict__ Xres) {
  __shared__ __align__(16) bf16 As[128][72];
  __shared__ __align__(16) bf16 Bs[128][72];
  int t = threadIdx.x, l = t & 63, wid = t >> 6;
  int ln = l & 15, grp = l >> 4;
  int m0 = blockIdx.y * 128, n0 = blockIdx.x * 128;
  int wr = wid >> 1, wc = wid & 1;
  f32x4 acc[4][4] = {};
  int srow = t >> 1, shalf = (t & 1) * 32;

  for (int kt = 0; kt < 16; ++kt) {
    int k0 = kt * 64;
    const bf16* asrc = A + (size_t)(m0 + srow) * 1024 + k0 + shalf;
    const bf16* bsrc = Bw + (size_t)(n0 + srow) * 1024 + k0 + shalf;
    bf16x8 a0 = ((const bf16x8*)asrc)[0], a1 = ((const bf16x8*)asrc)[1];
    bf16x8 a2 = ((const bf16x8*)asrc)[2], a3 = ((const bf16x8*)asrc)[3];
    bf16x8 b0 = ((const bf16x8*)bsrc)[0], b1 = ((const bf16x8*)bsrc)[1];
    bf16x8 b2 = ((const bf16x8*)bsrc)[2], b3 = ((const bf16x8*)bsrc)[3];
    __syncthreads();
    *(bf16x8*)&As[srow][shalf + 0] = a0;  *(bf16x8*)&As[srow][shalf + 8] = a1;
    *(bf16x8*)&As[srow][shalf + 16] = a2; *(bf16x8*)&As[srow][shalf + 24] = a3;
    *(bf16x8*)&Bs[srow][shalf + 0] = b0;  *(bf16x8*)&Bs[srow][shalf + 8] = b1;
    *(bf16x8*)&Bs[srow][shalf + 16] = b2; *(bf16x8*)&Bs[srow][shalf + 24] = b3;
    __syncthreads();
#pragma unroll
    for (int ks = 0; ks < 2; ++ks) {
      int kk = ks * 32 + grp * 8;
      bf16x8 af[4], bf[4];
#pragma unroll
      for (int is = 0; is < 4; ++is) af[is] = *(const bf16x8*)&As[wr * 64 + is * 16 + ln][kk];
#pragma unroll
      for (int js = 0; js < 4; ++js) bf[js] = *(const bf16x8*)&Bs[wc * 64 + js * 16 + ln][kk];
#pragma unroll
      for (int is = 0; is < 4; ++is)
#pragma unroll
        for (int js = 0; js < 4; ++js) acc[is][js] = MFMA16(af[is], bf[js], acc[is][js]);
    }
  }

#pragma unroll
  for (int is = 0; is < 4; ++is)
#pragma unroll
    for (int js = 0; js < 4; ++js)
#pragma unroll
      for (int r = 0; r < 4; ++r) {
        int m = m0 + wr * 64 + is * 16 + grp * 4 + r;
        int n = n0 + wc * 64 + js * 16 + ln;
        float v = acc[is][js][r];
        if (MODE == 0) {
          int b = m >> 7, il = m & 127;
          if (n < 1024) {
            int h = n >> 6, dm = n & 63;
            Qb[((size_t)(b * 16 + h) * 128 + il) * 64 + dm] = (bf16)((v + bq[n]) * 0.125f);
          } else if (n < 2048) {
            Kn[(size_t)m * 1024 + (n - 1024)] = (bf16)v;
          } else if (n < 3072) {
            Vn[(size_t)m * 1024 + (n - 2048)] = (bf16)v;
          } else if (n < 3232) {
            int e = n - 3072, hh = e / 10, nb = e - hh * 10;
            Rws[((size_t)(b * 16 + hh) * 128 + il) * 10 + nb] = v + br[e];
          }
        } else {
          Out[(size_t)m * 1024 + n] = v + bproj[n] + Xres[(size_t)m * 1024 + n];
        }
      }
}

// ============ attention: grid = 128 bh * 6 chunks, 512 threads ============
// 2 barriers/tile; per-wave G window folded in place into Sacc; P aliased into Gw
// (LDS 50176B -> 3 blocks/CU). NOTE: launch_bounds (512,4) NOT (512,6): the ,6 pin
// (85-VGPR cap) collapses the allocator to 40 VGPR + 360MB scratch (R3-R5 evidence);
// unpinned, this state fits 64 VGPR naturally (R2) and 64*6waves/SIMD fits the pool.
__global__ __launch_bounds__(512, 4) void k_attn(const float* __restrict__ cacheK,
                                                 const float* __restrict__ cacheV,
                                                 const bf16* __restrict__ Kn,
                                                 const bf16* __restrict__ Vn,
                                                 const bf16* __restrict__ Qb,
                                                 const float* __restrict__ Rws,
                                                 const float* __restrict__ bnd,
                                                 float* __restrict__ Opart,
                                                 float* __restrict__ mws,
                                                 float* __restrict__ lws) {
  __shared__ __align__(16) bf16 Ks[64][72];
  __shared__ __align__(16) bf16 Vt[64][72];       // Vt[d][j]
  __shared__ __align__(16) bf16 Gw[8][80][20];    // per-wave: [c_local][i_local]; P reuses this
  __shared__ __align__(16) bf16 bT[192][16];      // bT[c][n] = bnd[n][dlo+c]

  int t = threadIdx.x, l = t & 63, w = t >> 6;
  int grp = l >> 4, ln = l & 15;
  int s = blockIdx.x % 6, bh = blockIdx.x / 6;
  int b = bh >> 4, h = bh & 15;

  if (t < 192) {
#pragma unroll
    for (int e = 10; e < 16; ++e) bT[t][e] = (bf16)0.f;
  }

  int iq = w * 16 + ln;
  bf16x8 qf[2];
  qf[0] = *(const bf16x8*)(Qb + ((size_t)bh * 128 + iq) * 64 + grp * 8);
  qf[1] = *(const bf16x8*)(Qb + ((size_t)bh * 128 + iq) * 64 + 32 + grp * 8);
  bf16x8 rf;
  {
    union { bf16 hh[8]; bf16x8 v; } u;
    const float* rrow = Rws + ((size_t)bh * 128 + iq) * 10;
#pragma unroll
    for (int e = 0; e < 8; ++e) {
      int k = grp * 8 + e;
      u.hh[e] = (bf16)(k < 10 ? rrow[k] : 0.f);
    }
    rf = u.v;
  }

  // staging thread roles
  int krow = t >> 3, kcb = (t & 7) * 8;   // K: 64 rows x 8 col-blocks
  int vjl = t & 63, vd0 = (t >> 6) * 8;   // V: 64 j x 8 d-blocks
  int bc = t >> 1, bnh = (t & 1) * 5;     // bnd: threads<384, 5 basis each

  // uniform fp32 double-buffer staging regs
  float4 kA, kB, vA, vB;
  float bnv[5];

  auto issue = [&](int jt0) {
    if (jt0 < 4096) {
      const float* src = cacheK + ((size_t)(b * 4096 + jt0 + krow)) * 1024 + h * 64 + kcb;
      kA = *(const float4*)src;
      kB = *(const float4*)(src + 4);
      const float* sv = cacheV + ((size_t)(b * 4096 + jt0 + vjl)) * 1024 + h * 64 + vd0;
      vA = *(const float4*)sv;
      vB = *(const float4*)(sv + 4);
    } else {
      // new-token tiles (L2-hot, minority path): convert bf16 -> fp32 staging regs
      bf16x8 kN = *(const bf16x8*)(Kn + ((size_t)(b * 128 + (jt0 + krow - 4096))) * 1024 + h * 64 + kcb);
      bf16x8 vN = *(const bf16x8*)(Vn + ((size_t)(b * 128 + (jt0 + vjl - 4096))) * 1024 + h * 64 + vd0);
      kA = make_float4((float)kN[0], (float)kN[1], (float)kN[2], (float)kN[3]);
      kB = make_float4((float)kN[4], (float)kN[5], (float)kN[6], (float)kN[7]);
      vA = make_float4((float)vN[0], (float)vN[1], (float)vN[2], (float)vN[3]);
      vB = make_float4((float)vN[4], (float)vN[5], (float)vN[6], (float)vN[7]);
    }
    if (t < 384) {
      int d = (4033 - jt0) + bc;
      d = d < 0 ? 0 : (d > 4095 ? 4095 : d);
#pragma unroll
      for (int k = 0; k < 5; ++k) bnv[k] = bnd[(size_t)(bnh + k) * 4096 + d];
    }
  };

  issue(s * 704);

  f32x4 Oacc[4] = {};
  float m_r[4], l_r[4];
#pragma unroll
  for (int r = 0; r < 4; ++r) { m_r[r] = -1e30f; l_r[r] = 0.f; }

  for (int tt = 0; tt < 11; ++tt) {
    int jt0 = s * 704 + tt * 64;
    __syncthreads();                 // all waves done reading previous tile's LDS
    // ---- write staged regs -> LDS (uniform path) ----
    *(bf16x8*)&Ks[krow][kcb] = cvt8(kA, kB);
    Vt[vd0 + 0][vjl] = (bf16)vA.x; Vt[vd0 + 1][vjl] = (bf16)vA.y;
    Vt[vd0 + 2][vjl] = (bf16)vA.z; Vt[vd0 + 3][vjl] = (bf16)vA.w;
    Vt[vd0 + 4][vjl] = (bf16)vB.x; Vt[vd0 + 5][vjl] = (bf16)vB.y;
    Vt[vd0 + 6][vjl] = (bf16)vB.z; Vt[vd0 + 7][vjl] = (bf16)vB.w;
    if (t < 384) {
#pragma unroll
      for (int k = 0; k < 5; ++k) bT[bc][bnh + k] = (bf16)bnv[k];
    }
    __syncthreads();                 // staging visible to all
    if (tt + 1 < 11) issue(jt0 + 64);  // prefetch next tile

    // ---- S = Q @ K^T ----
    __builtin_amdgcn_s_setprio(1);
    f32x4 Sacc[4] = {};
#pragma unroll
    for (int ks = 0; ks < 2; ++ks) {
      int kk = ks * 32 + grp * 8;
#pragma unroll
      for (int js = 0; js < 4; ++js) {
        bf16x8 bfr = *(const bf16x8*)&Ks[js * 16 + ln][kk];
        Sacc[js] = MFMA16(qf[ks], bfr, Sacc[js]);
      }
    }
    // ---- per-wave G window: c in [w*16, w*16+80) ----
#pragma unroll
    for (int u = 0; u < 5; ++u) {
      bf16x8 bfr = *(const bf16x8*)&bT[(w + u) * 16 + ln][grp * 8];
      f32x4 z = {};
      f32x4 g = MFMA16(rf, bfr, z);
      union { bf16 hh[4]; u16x4 v; } uu;
      uu.hh[0] = (bf16)g[0]; uu.hh[1] = (bf16)g[1];
      uu.hh[2] = (bf16)g[2]; uu.hh[3] = (bf16)g[3];
      *(u16x4*)&Gw[w][u * 16 + ln][grp * 4] = uu.v;
    }
    __builtin_amdgcn_s_setprio(0);

    // ---- fold G + mask into Sacc IN PLACE (all Gw reads before any P write) ----
#pragma unroll
    for (int r = 0; r < 4; ++r) {
      int irow = grp * 4 + r;
      int il = w * 16 + irow;
#pragma unroll
      for (int js = 0; js < 4; ++js) {
        int jj = js * 16 + ln;
        int d = 4096 + il - (jt0 + jj);
        bool valid = ((unsigned)d) < 4096u;
        int cl = 63 + irow - jj;          // in [0,79) always
        float g = (float)Gw[w][cl][irow];
        Sacc[js][r] = valid ? (Sacc[js][r] + g) : -1e9f;
      }
    }
    // ---- online softmax; write P into Gw[w] region (wave-private) ----
    bf16* Pw = (bf16*)&Gw[w][0][0];    // P[i_local][j], pitch 72
#pragma unroll
    for (int r = 0; r < 4; ++r) {
      int irow = grp * 4 + r;
      float mx = fmaxf(fmaxf(Sacc[0][r], Sacc[1][r]), fmaxf(Sacc[2][r], Sacc[3][r]));
#pragma unroll
      for (int off = 1; off < 16; off <<= 1) mx = fmaxf(mx, __shfl_xor(mx, off));
      float mnew = fmaxf(m_r[r], mx);
      float sc = __expf(m_r[r] - mnew);
      m_r[r] = mnew;
      float rs = 0.f;
#pragma unroll
      for (int js = 0; js < 4; ++js) {
        float p = __expf(Sacc[js][r] - mnew);
        rs += p;
        Pw[irow * 72 + js * 16 + ln] = (bf16)p;
      }
#pragma unroll
      for (int off = 1; off < 16; off <<= 1) rs += __shfl_xor(rs, off);
      l_r[r] = l_r[r] * sc + rs;
#pragma unroll
      for (int ds = 0; ds < 4; ++ds) Oacc[ds][r] *= sc;
    }

    // ---- O += P @ V (reads own wave's P; same-wave DS ordering) ----
    __builtin_amdgcn_s_setprio(1);
    {
      bf16x8 pa0 = *(const bf16x8*)&Pw[ln * 72 + grp * 8];
      bf16x8 pa1 = *(const bf16x8*)&Pw[ln * 72 + 32 + grp * 8];
#pragma unroll
      for (int ds = 0; ds < 4; ++ds) {
        bf16x8 v0 = *(const bf16x8*)&Vt[ds * 16 + ln][grp * 8];
        bf16x8 v1 = *(const bf16x8*)&Vt[ds * 16 + ln][32 + grp * 8];
        Oacc[ds] = MFMA16(pa0, v0, Oacc[ds]);
        Oacc[ds] = MFMA16(pa1, v1, Oacc[ds]);
      }
    }
    __builtin_amdgcn_s_setprio(0);
  }

  int part = s * 128 + bh;
#pragma unroll
  for (int ds = 0; ds < 4; ++ds)
#pragma unroll
    for (int r = 0; r < 4; ++r) {
      int il = w * 16 + grp * 4 + r;
      Opart[((size_t)part * 128 + il) * 64 + ds * 16 + ln] = Oacc[ds][r];
    }
  if (ln == 0) {
#pragma unroll
    for (int r = 0; r < 4; ++r) {
      int il = w * 16 + grp * 4 + r;
      mws[(size_t)part * 128 + il] = m_r[r];
      lws[(size_t)part * 128 + il] = l_r[r];
    }
  }
}

// ============ split-K combine -> A (merged heads, bf16) ============
__global__ __launch_bounds__(256) void k_combine(const float* __restrict__ Opart,
                                                 const float* __restrict__ mws,
                                                 const float* __restrict__ lws,
                                                 bf16* __restrict__ Aout) {
  int bh = blockIdx.x, q = blockIdx.y, t = threadIdx.x;
  int dm = t & 63, iq = t >> 6;
  int b = bh >> 4, h = bh & 15;
  for (int ii = 0; ii < 8; ++ii) {
    int i = q * 32 + iq * 8 + ii;
    float ms[6], M = -1e30f;
#pragma unroll
    for (int s = 0; s < 6; ++s) {
      ms[s] = mws[(size_t)(s * 128 + bh) * 128 + i];
      M = fmaxf(M, ms[s]);
    }
    float L = 0.f, acc = 0.f;
#pragma unroll
    for (int s = 0; s < 6; ++s) {
      float wgt = __expf(ms[s] - M);
      L += wgt * lws[(size_t)(s * 128 + bh) * 128 + i];
      acc += wgt * Opart[((size_t)(s * 128 + bh) * 128 + i) * 64 + dm];
    }
    Aout[((size_t)(b * 128 + i)) * 1024 + h * 64 + dm] = (bf16)(acc / L);
  }
}

extern "C" void kernel_launch(void* const* d_in, const int* in_sizes, int n_in,
                              void* d_out, int out_size, void* d_ws, size_t ws_size,
                              hipStream_t stream) {
  (void)in_sizes; (void)n_in; (void)out_size; (void)ws_size;
  const float* X      = (const float*)d_in[0];
  const float* cacheK = (const float*)d_in[1];
  const float* cacheV = (const float*)d_in[2];
  const float* Wq     = (const float*)d_in[3];
  const float* bq     = (const float*)d_in[4];
  const float* Wk     = (const float*)d_in[5];
  const float* Wv     = (const float*)d_in[6];
  const float* Wproj  = (const float*)d_in[7];
  const float* bproj  = (const float*)d_in[8];
  const float* Wr     = (const float*)d_in[9];
  const float* br     = (const float*)d_in[10];
  const float* bnd    = (const float*)d_in[11];
  const float* lng    = (const float*)d_in[12];
  const float* lnb    = (const float*)d_in[13];
  float* out = (float*)d_out;

  char* ws = (char*)d_ws;
  bf16* Wt_all = (bf16*)ws;  ws += (size_t)3328 * 1024 * 2;
  bf16* Wpt    = (bf16*)ws;  ws += (size_t)1024 * 1024 * 2;
  bf16* Xn     = (bf16*)ws;  ws += (size_t)1024 * 1024 * 2;
  bf16* Qb     = (bf16*)ws;  ws += (size_t)1024 * 1024 * 2;
  bf16* Kn     = (bf16*)ws;  ws += (size_t)1024 * 1024 * 2;
  bf16* Vn     = (bf16*)ws;  ws += (size_t)1024 * 1024 * 2;
  bf16* Aattn  = (bf16*)ws;  ws += (size_t)1024 * 1024 * 2;
  float* Rws   = (float*)ws; ws += (size_t)128 * 128 * 10 * 4;
  float* mws   = (float*)ws; ws += (size_t)6 * 128 * 128 * 4;
  float* lws   = (float*)ws; ws += (size_t)6 * 128 * 128 * 4;
  float* Opart = (float*)ws; ws += (size_t)6 * 128 * 128 * 64 * 4;

  k_convert<<<dim3(68 * 16), 256, 0, stream>>>(Wq, Wk, Wv, Wr, Wproj, Wt_all, Wpt);
  k_ln<<<dim3(1024), 256, 0, stream>>>(X, lng, lnb, Xn);
  k_gemm<0><<<dim3(26, 8), 256, 0, stream>>>(Xn, Wt_all, Qb, Kn, Vn, Rws, bq, br,
                                             nullptr, nullptr, nullptr);
  k_attn<<<dim3(768), 512, 0, stream>>>(cacheK, cacheV, Kn, Vn, Qb, Rws, bnd,
                                        Opart, mws, lws);
  k_combine<<<dim3(128, 4), 256, 0, stream>>>(Opart, mws, lws, Aattn);
  k_gemm<1><<<dim3(8, 8), 256, 0, stream>>>(Aattn, Wpt, nullptr, nullptr, nullptr,
                                            nullptr, nullptr, nullptr, out, bproj, X);
}